// Round 4
// baseline (1397.921 us; speedup 1.0000x reference)
//
#include <hip/hip_runtime.h>
#include <stdint.h>

#define B_   128
#define T_   500
#define C_   700
#define CP_  704          // C padded to 16
#define H_   1024
#define O_   20
#define M_   (T_ * B_)    // 64000 rows, row = t*128 + b
#define KA_  (2 * CP_)    // 1408: A' = [hi | lo]
#define KB_  (3 * CP_)    // 2112: Bt = [hi | hi | lo]
#define SCALE_      256.0f
#define INV_SCALE2_ (1.0f / 65536.0f)

typedef _Float16 half8 __attribute__((ext_vector_type(8)));
typedef float    f32x4 __attribute__((ext_vector_type(4)));

// ---------------------------------------------------------------------------
// out[c*R + r] = (c < C) ? in[r*C + c] : 0   (fp32 transpose, zero-pad)
__global__ __launch_bounds__(256) void transpose_pad(
    const float* __restrict__ in, float* __restrict__ out,
    int R, int C, int Cpad) {
  int idx = blockIdx.x * 256 + threadIdx.x;
  if (idx >= Cpad * R) return;
  int c = idx / R;
  int r = idx - c * R;
  out[idx] = (c < C) ? in[(size_t)r * C + c] : 0.0f;
}

// ---------------------------------------------------------------------------
// Bt[n][k]: k in [0,704) -> hi(w*256); [704,1408) -> hi; [1408,2112) -> lo
__global__ __launch_bounds__(256) void bt_prep(
    const float* __restrict__ w_in, _Float16* __restrict__ Bt) {
  int idx = blockIdx.x * 256 + threadIdx.x;   // over H_*KB_
  if (idx >= H_ * KB_) return;
  int n = idx / KB_;
  int k = idx - n * KB_;
  int blk = k / CP_;
  int c = k - blk * CP_;
  float v = (c < C_) ? w_in[(size_t)n * C_ + c] * SCALE_ : 0.0f;
  _Float16 hi = (_Float16)v;
  Bt[idx] = (blk == 2) ? (_Float16)(v - (float)hi) : hi;
}

// ---------------------------------------------------------------------------
// A3[m][k]: k in [0,704) -> hi(xd*256); [704,1408) -> lo.  m = t*128+b.
__global__ __launch_bounds__(256) void delay_split(
    const float* __restrict__ x, const int* __restrict__ delays,
    _Float16* __restrict__ A3) {
  int row = blockIdx.x;
  int t = row >> 7;
  int b = row & 127;
  const float* xb = x + (size_t)b * (T_ * C_);
  _Float16* dst = A3 + (size_t)row * KA_;
  for (int c = threadIdx.x; c < CP_; c += 256) {
    float v = 0.0f;
    if (c < C_) {
      int ts = t - delays[c];
      if (ts >= 0) v = xb[(size_t)ts * C_ + c];
    }
    v *= SCALE_;
    _Float16 hi = (_Float16)v;
    dst[c] = hi;
    dst[CP_ + c] = (_Float16)(v - (float)hi);
  }
}

// ---------------------------------------------------------------------------
__device__ __forceinline__ void gload16(const void* g, const void* l) {
  __builtin_amdgcn_global_load_lds(
      (const __attribute__((address_space(1))) void*)(uintptr_t)g,
      (__attribute__((address_space(3))) void*)(uint32_t)(uintptr_t)l,
      16, 0, 0);
}

// fp16 MFMA GEMM: Cm[M_,H_] = A3[M_,KA_ (hi reused)] x Bt[H_,KB_]^T, *2^-16.
__global__ __launch_bounds__(256) void gemm_split(
    const _Float16* __restrict__ A3, const _Float16* __restrict__ Bt,
    float* __restrict__ Cm) {
  __shared__ __align__(16) _Float16 As[128 * 32];
  __shared__ __align__(16) _Float16 Bs[128 * 32];

  const int tid  = threadIdx.x;
  const int wave = tid >> 6, lane = tid & 63;
  const int col0 = blockIdx.x * 128;
  const int row0 = blockIdx.y * 128;
  const int q = lane >> 4, r = lane & 15;
  const int wm0 = (wave >> 1) * 64, wn0 = (wave & 1) * 64;

  f32x4 acc[4][4] = {};

  const int pi0 = wave * 2;
  const int srow = lane >> 2;
  const int gch8 = (((lane & 3) ^ ((lane >> 3) & 3))) * 8;

  const int ch8 = (q ^ ((r >> 1) & 3)) * 8;
  int aoff[4], boff[4];
#pragma unroll
  for (int i = 0; i < 4; ++i) {
    aoff[i] = (wm0 + i * 16 + r) * 32 + ch8;
    boff[i] = (wn0 + i * 16 + r) * 32 + ch8;
  }

  const size_t arow0 = (size_t)(row0 + pi0 * 16 + srow);
  const size_t arow1 = arow0 + 16;
  const size_t brow0 = (size_t)(col0 + pi0 * 16 + srow);
  const size_t brow1 = brow0 + 16;

  for (int kb = 0; kb < KB_ / 32; ++kb) {
    const int k0 = kb * 32;
    const int kA = (k0 < KA_) ? k0 : (k0 - KA_);
    __syncthreads();
    gload16(A3 + arow0 * KA_ + kA + gch8, &As[(pi0 + 0) * 512]);
    gload16(A3 + arow1 * KA_ + kA + gch8, &As[(pi0 + 1) * 512]);
    gload16(Bt + brow0 * KB_ + k0 + gch8, &Bs[(pi0 + 0) * 512]);
    gload16(Bt + brow1 * KB_ + k0 + gch8, &Bs[(pi0 + 1) * 512]);
    __syncthreads();

    half8 af[4], bf[4];
#pragma unroll
    for (int i = 0; i < 4; ++i) af[i] = *(const half8*)&As[aoff[i]];
#pragma unroll
    for (int j = 0; j < 4; ++j) bf[j] = *(const half8*)&Bs[boff[j]];
#pragma unroll
    for (int i = 0; i < 4; ++i)
#pragma unroll
      for (int j = 0; j < 4; ++j)
        acc[i][j] = __builtin_amdgcn_mfma_f32_16x16x32_f16(af[i], bf[j],
                                                           acc[i][j], 0, 0, 0);
  }

#pragma unroll
  for (int i = 0; i < 4; ++i) {
    const int mrow = row0 + wm0 + i * 16 + q * 4;
#pragma unroll
    for (int j = 0; j < 4; ++j) {
      const int ncol = col0 + wn0 + j * 16 + r;
      float* cp = Cm + (size_t)mrow * H_ + ncol;
#pragma unroll
      for (int rg = 0; rg < 4; ++rg)
        cp[(size_t)rg * H_] = acc[i][j][rg] * INV_SCALE2_;
    }
  }
}

// ---------------------------------------------------------------------------
// One wave per batch sample; 16 neurons per lane (h = lane*16 + j).
// Spike list lives in LDS, built wave-synchronously with ballot + prefix
// rank (no atomics, no barriers, no address-taken locals -> no scratch).
// Gather loop reads 4 indices/batch via one ds_read_b128 (uniform addr =
// broadcast), issues all 16 float4 row loads + 4 wout scalars, drains once.
// w_out gather merged by deferring the readout filter one step (R3 scheme).
__global__ __launch_bounds__(64, 1) void recurrent_w(
    const float* __restrict__ Iin,   // [M_][H_], row = t*128 + b
    const float* __restrict__ wrecT, // [H_][H_]  wrecT[h'][h] = w_rec[h][h']
    const float* __restrict__ woutT, // [H_][O_]  woutT[h][o]  = w_out[o][h]
    const float* __restrict__ alpha, const float* __restrict__ rho,
    const float* __restrict__ beta_a, const float* __restrict__ beta_out,
    float* __restrict__ out) {
  __shared__ __align__(16) int lstS[H_ + 8];

  const int b = blockIdx.x;
  const int lane = threadIdx.x;
  const int h0 = lane * 16;
  const unsigned long long lmask_lt = (1ull << lane) - 1ull;

  // zero-init list so tail reads are always in-range indices
  for (int i = lane; i < H_ + 8; i += 64) lstS[i] = 0;

  float v[16], av[16], spk[16];
  float al[16], al1[16], rh[16], rh1[16], ba[16];
#pragma unroll
  for (int j = 0; j < 16; ++j) {
    v[j] = 0.f; av[j] = 0.f; spk[j] = 0.f;
    al[j] = alpha[h0 + j]; al1[j] = 1.0f - al[j];
    rh[j] = rho[h0 + j];   rh1[j] = 1.0f - rh[j];
    ba[j] = beta_a[h0 + j];
  }

  const int olane = (lane < O_) ? lane : 0;
  float bo = 0.f, vo = 0.f, osum = 0.f;
  if (lane < O_) bo = beta_out[lane];

  const float* base = Iin + (size_t)b * H_ + h0;
  float4 nx0 = *(const float4*)(base + 0);
  float4 nx1 = *(const float4*)(base + 4);
  float4 nx2 = *(const float4*)(base + 8);
  float4 nx3 = *(const float4*)(base + 12);

  int total = 0;   // spike count of previous step's set S(t-1)

  for (int t = 0; t < T_; ++t) {
    float I[16];
    I[0]  = nx0.x; I[1]  = nx0.y; I[2]  = nx0.z; I[3]  = nx0.w;
    I[4]  = nx1.x; I[5]  = nx1.y; I[6]  = nx1.z; I[7]  = nx1.w;
    I[8]  = nx2.x; I[9]  = nx2.y; I[10] = nx2.z; I[11] = nx2.w;
    I[12] = nx3.x; I[13] = nx3.y; I[14] = nx3.z; I[15] = nx3.w;

    // ---- batched gather over S(t-1) from the LDS list ----
    float io = 0.f;   // deferred readout current of S(t-1)
    for (int s = 0; s < total; s += 4) {
      const int4 idx4 = *(const int4*)&lstS[s];
      const int hA = __builtin_amdgcn_readfirstlane(idx4.x & (H_ - 1));
      const int hB = __builtin_amdgcn_readfirstlane(idx4.y & (H_ - 1));
      const int hC = __builtin_amdgcn_readfirstlane(idx4.z & (H_ - 1));
      const int hD = __builtin_amdgcn_readfirstlane(idx4.w & (H_ - 1));
      const float sB = (s + 1 < total) ? 1.f : 0.f;
      const float sC = (s + 2 < total) ? 1.f : 0.f;
      const float sD = (s + 3 < total) ? 1.f : 0.f;

      // issue ALL loads before any accumulation (single vmcnt drain)
      const float* rA = wrecT + (size_t)hA * H_ + h0;
      const float* rB = wrecT + (size_t)hB * H_ + h0;
      const float* rC = wrecT + (size_t)hC * H_ + h0;
      const float* rD = wrecT + (size_t)hD * H_ + h0;
      float4 wA0 = *(const float4*)(rA + 0),  wA1 = *(const float4*)(rA + 4);
      float4 wA2 = *(const float4*)(rA + 8),  wA3 = *(const float4*)(rA + 12);
      float4 wB0 = *(const float4*)(rB + 0),  wB1 = *(const float4*)(rB + 4);
      float4 wB2 = *(const float4*)(rB + 8),  wB3 = *(const float4*)(rB + 12);
      float4 wC0 = *(const float4*)(rC + 0),  wC1 = *(const float4*)(rC + 4);
      float4 wC2 = *(const float4*)(rC + 8),  wC3 = *(const float4*)(rC + 12);
      float4 wD0 = *(const float4*)(rD + 0),  wD1 = *(const float4*)(rD + 4);
      float4 wD2 = *(const float4*)(rD + 8),  wD3 = *(const float4*)(rD + 12);
      const float oA = woutT[(size_t)hA * O_ + olane];
      const float oB = woutT[(size_t)hB * O_ + olane];
      const float oC = woutT[(size_t)hC * O_ + olane];
      const float oD = woutT[(size_t)hD * O_ + olane];

      I[0] += wA0.x; I[1] += wA0.y; I[2]  += wA0.z; I[3]  += wA0.w;
      I[4] += wA1.x; I[5] += wA1.y; I[6]  += wA1.z; I[7]  += wA1.w;
      I[8] += wA2.x; I[9] += wA2.y; I[10] += wA2.z; I[11] += wA2.w;
      I[12]+= wA3.x; I[13]+= wA3.y; I[14] += wA3.z; I[15] += wA3.w;
      io += oA;
      I[0]  = fmaf(sB, wB0.x, I[0]);  I[1]  = fmaf(sB, wB0.y, I[1]);
      I[2]  = fmaf(sB, wB0.z, I[2]);  I[3]  = fmaf(sB, wB0.w, I[3]);
      I[4]  = fmaf(sB, wB1.x, I[4]);  I[5]  = fmaf(sB, wB1.y, I[5]);
      I[6]  = fmaf(sB, wB1.z, I[6]);  I[7]  = fmaf(sB, wB1.w, I[7]);
      I[8]  = fmaf(sB, wB2.x, I[8]);  I[9]  = fmaf(sB, wB2.y, I[9]);
      I[10] = fmaf(sB, wB2.z, I[10]); I[11] = fmaf(sB, wB2.w, I[11]);
      I[12] = fmaf(sB, wB3.x, I[12]); I[13] = fmaf(sB, wB3.y, I[13]);
      I[14] = fmaf(sB, wB3.z, I[14]); I[15] = fmaf(sB, wB3.w, I[15]);
      io = fmaf(sB, oB, io);
      I[0]  = fmaf(sC, wC0.x, I[0]);  I[1]  = fmaf(sC, wC0.y, I[1]);
      I[2]  = fmaf(sC, wC0.z, I[2]);  I[3]  = fmaf(sC, wC0.w, I[3]);
      I[4]  = fmaf(sC, wC1.x, I[4]);  I[5]  = fmaf(sC, wC1.y, I[5]);
      I[6]  = fmaf(sC, wC1.z, I[6]);  I[7]  = fmaf(sC, wC1.w, I[7]);
      I[8]  = fmaf(sC, wC2.x, I[8]);  I[9]  = fmaf(sC, wC2.y, I[9]);
      I[10] = fmaf(sC, wC2.z, I[10]); I[11] = fmaf(sC, wC2.w, I[11]);
      I[12] = fmaf(sC, wC3.x, I[12]); I[13] = fmaf(sC, wC3.y, I[13]);
      I[14] = fmaf(sC, wC3.z, I[14]); I[15] = fmaf(sC, wC3.w, I[15]);
      io = fmaf(sC, oC, io);
      I[0]  = fmaf(sD, wD0.x, I[0]);  I[1]  = fmaf(sD, wD0.y, I[1]);
      I[2]  = fmaf(sD, wD0.z, I[2]);  I[3]  = fmaf(sD, wD0.w, I[3]);
      I[4]  = fmaf(sD, wD1.x, I[4]);  I[5]  = fmaf(sD, wD1.y, I[5]);
      I[6]  = fmaf(sD, wD1.z, I[6]);  I[7]  = fmaf(sD, wD1.w, I[7]);
      I[8]  = fmaf(sD, wD2.x, I[8]);  I[9]  = fmaf(sD, wD2.y, I[9]);
      I[10] = fmaf(sD, wD2.z, I[10]); I[11] = fmaf(sD, wD2.w, I[11]);
      I[12] = fmaf(sD, wD3.x, I[12]); I[13] = fmaf(sD, wD3.y, I[13]);
      I[14] = fmaf(sD, wD3.z, I[14]); I[15] = fmaf(sD, wD3.w, I[15]);
      io = fmaf(sD, oD, io);
    }

    // prefetch next timestep (after gather issues; stays in flight)
    if (t + 1 < T_) {
      const float* nb = base + (size_t)(t + 1) * (B_ * H_);
      nx0 = *(const float4*)(nb + 0);
      nx1 = *(const float4*)(nb + 4);
      nx2 = *(const float4*)(nb + 8);
      nx3 = *(const float4*)(nb + 12);
    }

    // deferred readout filter: applies io(S(t-1)); t=0 contributes exact 0
    vo = bo * vo + (1.0f - bo) * io;
    osum += vo;

    // adaptive LIF update + ballot compaction into the LDS list
    int ntot = 0;
#pragma unroll
    for (int j = 0; j < 16; ++j) {
      const float vg = (spk[j] > 0.f) ? 0.f : v[j];
      const float vn = al[j] * vg + al1[j] * (I[j] - av[j]);
      const float sn = (vn > 1.0f) ? 1.0f : 0.0f;
      av[j] = rh[j] * av[j] + rh1[j] * (ba[j] * vn + sn);
      v[j] = vn; spk[j] = sn;
      const unsigned long long m = __ballot(vn > 1.0f);
      if (sn > 0.f) {
        const int pos = ntot + (int)__popcll(m & lmask_lt);
        lstS[pos] = h0 + j;
      }
      ntot += (int)__popcll(m);
    }
    total = ntot;
  }

  // epilogue: readout contribution of the final spike set S(T-1)
  {
    float io = 0.f;
    for (int s = 0; s < total; ++s)
      io += woutT[(size_t)(lstS[s] & (H_ - 1)) * O_ + olane];
    vo = bo * vo + (1.0f - bo) * io;
    osum += vo;
  }

  if (lane < O_) out[(size_t)b * O_ + lane] = osum / (float)T_;
}

// ---------------------------------------------------------------------------
extern "C" void kernel_launch(void* const* d_in, const int* in_sizes, int n_in,
                              void* d_out, int out_size, void* d_ws, size_t ws_size,
                              hipStream_t stream) {
  const float* x        = (const float*)d_in[0];
  const int*   delays   = (const int*)d_in[1];
  const float* w_in     = (const float*)d_in[2];
  const float* w_rec    = (const float*)d_in[3];
  const float* w_out    = (const float*)d_in[4];
  const float* alpha    = (const float*)d_in[5];
  const float* rho      = (const float*)d_in[6];
  const float* beta_a   = (const float*)d_in[7];
  const float* beta_out = (const float*)d_in[8];

  float* ws    = (float*)d_ws;
  float* wrecT = ws;                                 // H*H fp32
  float* woutT = wrecT + (size_t)H_ * H_;            // H*O fp32
  float* Iin   = woutT + (size_t)H_ * O_;            // M*H fp32
  _Float16* A3 = (_Float16*)(Iin + (size_t)M_ * H_); // M*KA fp16
  _Float16* Bt = A3 + (size_t)M_ * KA_;              // H*KB fp16
  float* out   = (float*)d_out;

  transpose_pad<<<(H_ * H_) / 256, 256, 0, stream>>>(w_rec, wrecT, H_, H_, H_);
  transpose_pad<<<(H_ * O_) / 256, 256, 0, stream>>>(w_out, woutT, O_, H_, H_);
  bt_prep<<<(H_ * KB_) / 256, 256, 0, stream>>>(w_in, Bt);
  delay_split<<<M_, 256, 0, stream>>>(x, delays, A3);

  dim3 g(H_ / 128, M_ / 128);
  gemm_split<<<g, 256, 0, stream>>>(A3, Bt, Iin);

  recurrent_w<<<B_, 64, 0, stream>>>(Iin, wrecT, woutT,
                                     alpha, rho, beta_a, beta_out, out);
}